// Round 15
// baseline (104.319 us; speedup 1.0000x reference)
//
#include <hip/hip_runtime.h>

#define RTOT 12960      // 4 * 3240 rows
#define PAIRS 3240
#define NB_VAR 81
#define HID 256
#define EPS 1e-5f

#define BM 64
#define BN 64
#define LDB 264        // sB row stride in bf16: 528 B/row -> 2-way bank alias max (free per m136)
#define NCPY 16        // GEMM-stage stats split (atomics, zeroed by k_init)
#define IBLK 40        // init blocks: 40 x 324 rows = 12960; exclusive non-atomic stats copies
#define IROWS 324
#define S0SZ (IBLK * 512)          // slot0: 40 copies (exclusive writes, no zeroing needed)
#define SLSZ (NCPY * 512)          // slots 1-4: 16 copies each (atomics, zeroed by k_init)

using bf8   = __attribute__((ext_vector_type(8))) short;
using f32x4 = __attribute__((ext_vector_type(4))) float;

__device__ inline ushort f2bf(float f) {
    union { float f; unsigned u; } c; c.f = f;
    unsigned u = c.u + 0x7fffu + ((c.u >> 16) & 1u);
    return (ushort)(u >> 16);
}
__device__ inline float bf2f(ushort h) {
    union { unsigned u; float f; } c; c.u = (unsigned)h << 16;
    return c.f;
}
__device__ inline unsigned pk2(float a, float b) {
    return (unsigned)f2bf(a) | ((unsigned)f2bf(b) << 16);
}
// upper-tri pair from linear index p (0..3239)
__device__ inline int2 pair_of(int p) {
    int i = (int)((161.0 - sqrt(25921.0 - 8.0 * (double)p)) * 0.5);
    if (i < 0) i = 0;
    while ((161 * (i + 1) - (i + 1) * (i + 1)) / 2 <= p) i++;
    while ((161 * i - i * i) / 2 > p) i--;
    int j = i + 1 + (p - (161 * i - i * i) / 2);
    return make_int2(i, j);
}

// sum ncpy split copies -> BN coefficients in LDS
__device__ __forceinline__ void coeffs(const float* __restrict__ st, int ncpy,
                                       const float* __restrict__ g,
                                       const float* __restrict__ beta,
                                       float* sS, float* sT) {
    int tid = threadIdx.x;
    float s = 0.f, q = 0.f;
    for (int cp = 0; cp < ncpy; cp++) {
        s += st[cp * 512 + tid];
        q += st[cp * 512 + 256 + tid];
    }
    float m = s * (1.f / RTOT);
    float v = q * (1.f / RTOT) - m * m;
    float sc = g[tid] * rsqrtf(v + EPS);
    sS[tid] = sc;
    sT[tid] = fmaf(-m, sc, beta[tid]);
}

// A-fragment: 8 bf16 from global, BN+ReLU in registers, repack bf16
__device__ __forceinline__ bf8 ldA(const ushort* xr, int kst,
                                   const float* sS, const float* sT) {
    float4 s0 = *(const float4*)&sS[kst], s1 = *(const float4*)&sS[kst + 4];
    float4 t0 = *(const float4*)&sT[kst], t1 = *(const float4*)&sT[kst + 4];
    ushort xv[8];
    *(uint4*)xv = *(const uint4*)(xr + kst);
    unsigned pk[4];
    pk[0] = pk2(fmaxf(fmaf(bf2f(xv[0]), s0.x, t0.x), 0.f),
                fmaxf(fmaf(bf2f(xv[1]), s0.y, t0.y), 0.f));
    pk[1] = pk2(fmaxf(fmaf(bf2f(xv[2]), s0.z, t0.z), 0.f),
                fmaxf(fmaf(bf2f(xv[3]), s0.w, t0.w), 0.f));
    pk[2] = pk2(fmaxf(fmaf(bf2f(xv[4]), s1.x, t1.x), 0.f),
                fmaxf(fmaf(bf2f(xv[5]), s1.y, t1.y), 0.f));
    pk[3] = pk2(fmaxf(fmaf(bf2f(xv[6]), s1.z, t1.z), 0.f),
                fmaxf(fmaf(bf2f(xv[7]), s1.w, t1.w), 0.f));
    return *(bf8*)pk;
}

// ---------------- init: weights->bf16, pairs, out-diag, proj + EXCLUSIVE stats0, zero slots 1-4 ----
// No atomics for stats0: block b owns rows [b*324, b*324+324) and writes its 512-float
// partial to its own slot (plain stores overwrite poison -> no memset dispatch needed).
__global__ __launch_bounds__(512) void k_init(
        const float* __restrict__ x, const float* __restrict__ w_in,
        const float* __restrict__ b_in,
        const float* __restrict__ w1, const float* __restrict__ w2,
        const float* __restrict__ w_out, ushort* __restrict__ wbf,
        int2* __restrict__ pairs, float* __restrict__ out,
        ushort* __restrict__ h0, float* __restrict__ stats) {
    __shared__ float feat[IROWS][4];
    __shared__ float part[2][2][256];
    int tid = threadIdx.x;
    int b = blockIdx.x;
    int gtid = b * 512 + tid;

    // weight conversion fp32 -> bf16 (row-major; layout: w1 | w2 | w_out)
    for (int i = gtid; i < 262144 + 81 * 256; i += IBLK * 512) {
        float v;
        if (i < 131072)      v = w1[i];
        else if (i < 262144) v = w2[i - 131072];
        else                 v = w_out[i - 262144];
        wbf[i] = f2bf(v);
    }
    // zero diagonal blocks of out
    for (int i = gtid; i < 4 * NB_VAR * 81; i += IBLK * 512) {
        int bb = i / (NB_VAR * 81);
        int rem = i - bb * (NB_VAR * 81);
        int ii = rem / 81, t = rem - ii * 81;
        out[((size_t)(bb * NB_VAR + ii) * NB_VAR + ii) * 81 + t] = 0.f;
    }
    // zero stats slots 1-4 (written later via atomics by the GEMM stages)
    for (int i = gtid; i < 4 * SLSZ; i += IBLK * 512)
        stats[S0SZ + i] = 0.f;

    // pair features for this block's 324 rows
    if (tid < IROWS) {
        int r = b * IROWS + tid;
        int bb = r / PAIRS, p = r - bb * PAIRS;
        int2 ij = pair_of(p);
        if (r < PAIRS) pairs[r] = ij;
        const float* xb = x + bb * NB_VAR * 2;
        feat[tid][0] = xb[ij.x * 2 + 0];
        feat[tid][1] = xb[ij.x * 2 + 1];
        feat[tid][2] = xb[ij.y * 2 + 0];
        feat[tid][3] = xb[ij.y * 2 + 1];
    }
    __syncthreads();

    int col = tid & 255, sub = tid >> 8;   // 2 subgroups x 162 rows
    float4 w = ((const float4*)w_in)[col];
    float bi = b_in[col];
    float s = 0.f, s2 = 0.f;
    int rl0 = sub * 162;
    for (int t = 0; t < 162; t++) {
        int rl = rl0 + t;
        float v = fmaf(feat[rl][0], w.x, fmaf(feat[rl][1], w.y,
                  fmaf(feat[rl][2], w.z, fmaf(feat[rl][3], w.w, bi))));
        v = fmaxf(v, 0.f);
        h0[(size_t)(b * IROWS + rl) * HID + col] = f2bf(v);
        s += v; s2 += v * v;
    }
    part[sub][0][col] = s;
    part[sub][1][col] = s2;
    __syncthreads();
    // exclusive per-block stats slot: [b][sub*256 + col], sub doubles as sum/sumsq selector
    stats[b * 512 + sub * 256 + col] = part[0][sub][col] + part[1][sub][col];
}

// ---------------- MFMA GEMM (R12 structure): LDS-B, wave strips, XCD swizzle ----------------
__global__ __launch_bounds__(256) void k_gemm(
        const ushort* __restrict__ X, const float* __restrict__ stin, int ncpyIn,
        const float* __restrict__ g, const float* __restrict__ beta,
        const ushort* __restrict__ Wb, const float* __restrict__ bias,
        const ushort* __restrict__ res, ushort* __restrict__ Y,
        float* __restrict__ stout) {
    __shared__ ushort sB[BN * LDB];
    __shared__ float sS[HID], sT[HID];
    __shared__ float sCS[4][BN], sCQ[4][BN];

    int tid = threadIdx.x;
    coeffs(stin, ncpyIn, g, beta, sS, sT);

    int id = blockIdx.x, bx, by;
    if (id < 800) { bx = (id >> 5) * 8 + (id & 7); by = (id >> 3) & 3; }
    else          { int j = id - 800; bx = 200 + (j >> 2); by = j & 3; }

    int bm0 = bx * BM;
    int bn0 = by * BN;
    {   // stage whole B tile: 64 rows x 256 k
        int row = tid >> 2, cq = tid & 3;
#pragma unroll
        for (int s = 0; s < 8; s++) {
            int col = cq * 8 + s * 32;
            uint4 wv = *(const uint4*)(Wb + (size_t)(bn0 + row) * HID + col);
            *(uint4*)&sB[row * LDB + col] = wv;
        }
    }
    __syncthreads();

    int lane = tid & 63, w = tid >> 6;
    int r16 = lane & 15, kq = lane >> 4;

    f32x4 acc[4] = {};
    int ar = min(bm0 + w * 16 + r16, RTOT - 1);
    const ushort* xr = X + (size_t)ar * HID;

#pragma unroll
    for (int kk = 0; kk < 8; kk++) {
        int kst = kk * 32 + kq * 8;
        bf8 af = ldA(xr, kst, sS, sT);
        bf8 b0 = *(const bf8*)&sB[(0 * 16 + r16) * LDB + kst];
        bf8 b1 = *(const bf8*)&sB[(1 * 16 + r16) * LDB + kst];
        bf8 b2 = *(const bf8*)&sB[(2 * 16 + r16) * LDB + kst];
        bf8 b3 = *(const bf8*)&sB[(3 * 16 + r16) * LDB + kst];
        acc[0] = __builtin_amdgcn_mfma_f32_16x16x32_bf16(af, b0, acc[0], 0, 0, 0);
        acc[1] = __builtin_amdgcn_mfma_f32_16x16x32_bf16(af, b1, acc[1], 0, 0, 0);
        acc[2] = __builtin_amdgcn_mfma_f32_16x16x32_bf16(af, b2, acc[2], 0, 0, 0);
        acc[3] = __builtin_amdgcn_mfma_f32_16x16x32_bf16(af, b3, acc[3], 0, 0, 0);
    }

    // epilogue: bias (+res), store bf16, column stats
    int rb = bm0 + w * 16;
#pragma unroll
    for (int n = 0; n < 4; n++) {
        int col = bn0 + n * 16 + r16;
        float bv = bias[col];
        float cs = 0.f, cq2 = 0.f;
#pragma unroll
        for (int i = 0; i < 4; i++) {
            int r = rb + kq * 4 + i;
            if (r < RTOT) {
                float v = acc[n][i] + bv;
                if (res) v += bf2f(res[(size_t)r * HID + col]);
                Y[(size_t)r * HID + col] = f2bf(v);
                cs += v; cq2 += v * v;
            }
        }
        cs += __shfl_xor(cs, 16); cq2 += __shfl_xor(cq2, 16);
        cs += __shfl_xor(cs, 32); cq2 += __shfl_xor(cq2, 32);
        if (lane < 16) {
            sCS[w][n * 16 + lane] = cs; sCQ[w][n * 16 + lane] = cq2;
        }
    }
    __syncthreads();
    if (tid < 2 * BN) {
        int col = tid & (BN - 1), q = tid >> 6;
        float v = q ? (sCQ[0][col] + sCQ[1][col] + sCQ[2][col] + sCQ[3][col])
                    : (sCS[0][col] + sCS[1][col] + sCS[2][col] + sCS[3][col]);
        int cp = id & (NCPY - 1);
        atomicAdd(&stout[cp * 512 + q * 256 + bn0 + col], v);
    }
}

// ---------------- final GEMM (N=81), wave strips, fused symmetric scatter ----------------
__global__ __launch_bounds__(256) void k_gout(
        const ushort* __restrict__ X, const float* __restrict__ stin,
        const float* __restrict__ g, const float* __restrict__ beta,
        const ushort* __restrict__ Wb, const float* __restrict__ b_out,
        const int2* __restrict__ pairs, float* __restrict__ out) {
    __shared__ ushort sB[BN * LDB];
    __shared__ float sS[HID], sT[HID];

    int tid = threadIdx.x;
    coeffs(stin, NCPY, g, beta, sS, sT);

    int id = blockIdx.x, bx, by;
    if (id < 400) { bx = (id >> 4) * 8 + (id & 7); by = (id >> 3) & 1; }
    else          { int j = id - 400; bx = 200 + (j >> 1); by = j & 1; }

    int bm0 = bx * BM;
    int bn0 = by * BN;
    {
        int row = tid >> 2, cq = tid & 3;
        int gn = bn0 + row; gn = gn < 81 ? gn : 80;
#pragma unroll
        for (int s = 0; s < 8; s++) {
            int col = cq * 8 + s * 32;
            uint4 wv = *(const uint4*)(Wb + (size_t)gn * HID + col);
            *(uint4*)&sB[row * LDB + col] = wv;
        }
    }
    __syncthreads();

    int lane = tid & 63, w = tid >> 6;
    int r16 = lane & 15, kq = lane >> 4;

    f32x4 acc[4] = {};
    int ar = min(bm0 + w * 16 + r16, RTOT - 1);
    const ushort* xr = X + (size_t)ar * HID;

#pragma unroll
    for (int kk = 0; kk < 8; kk++) {
        int kst = kk * 32 + kq * 8;
        bf8 af = ldA(xr, kst, sS, sT);
        bf8 b0 = *(const bf8*)&sB[(0 * 16 + r16) * LDB + kst];
        bf8 b1 = *(const bf8*)&sB[(1 * 16 + r16) * LDB + kst];
        bf8 b2 = *(const bf8*)&sB[(2 * 16 + r16) * LDB + kst];
        bf8 b3 = *(const bf8*)&sB[(3 * 16 + r16) * LDB + kst];
        acc[0] = __builtin_amdgcn_mfma_f32_16x16x32_bf16(af, b0, acc[0], 0, 0, 0);
        acc[1] = __builtin_amdgcn_mfma_f32_16x16x32_bf16(af, b1, acc[1], 0, 0, 0);
        acc[2] = __builtin_amdgcn_mfma_f32_16x16x32_bf16(af, b2, acc[2], 0, 0, 0);
        acc[3] = __builtin_amdgcn_mfma_f32_16x16x32_bf16(af, b3, acc[3], 0, 0, 0);
    }

    int rb = bm0 + w * 16;
#pragma unroll
    for (int n = 0; n < 4; n++) {
        int t = bn0 + n * 16 + r16;
        if (t >= 81) continue;
        int gi = t / 9, gj = t - gi * 9;
        int ttr = gj * 9 + gi;
        float bb = b_out[t];
#pragma unroll
        for (int i = 0; i < 4; i++) {
            int r = rb + kq * 4 + i;
            if (r >= RTOT) continue;
            int b = r / PAIRS, p = r - b * PAIRS;
            int2 ij = pairs[p];
            size_t base1 = ((size_t)(b * NB_VAR + ij.x) * NB_VAR + ij.y) * 81;
            size_t base2 = ((size_t)(b * NB_VAR + ij.y) * NB_VAR + ij.x) * 81;
            float v = acc[n][i] + bb;
            out[base1 + t] = v;
            out[base2 + ttr] = v;
        }
    }
}

extern "C" void kernel_launch(void* const* d_in, const int* in_sizes, int n_in,
                              void* d_out, int out_size, void* d_ws, size_t ws_size,
                              hipStream_t stream) {
    const float* x     = (const float*)d_in[0];
    const float* w_in  = (const float*)d_in[1];
    const float* b_in  = (const float*)d_in[2];
    const float* g1    = (const float*)d_in[3];
    const float* beta1 = (const float*)d_in[4];
    const float* w1    = (const float*)d_in[5];
    const float* bias1 = (const float*)d_in[6];
    const float* g2    = (const float*)d_in[7];
    const float* beta2 = (const float*)d_in[8];
    const float* w2    = (const float*)d_in[9];
    const float* bias2 = (const float*)d_in[10];
    const float* fg    = (const float*)d_in[11];
    const float* fbeta = (const float*)d_in[12];
    const float* w_out = (const float*)d_in[13];
    const float* b_out = (const float*)d_in[14];
    float* out = (float*)d_out;

    ushort* buf0 = (ushort*)d_ws;
    ushort* buf1 = buf0 + (size_t)RTOT * HID;
    ushort* buf2 = buf1 + (size_t)RTOT * HID;
    ushort* wbf  = buf2 + (size_t)RTOT * HID;   // 5*65536 elems (w1 | w2 | w_out row-major bf16)
    float* stats = (float*)(wbf + 5 * 65536);   // [S0: 40x512][S1..S4: 16x512 each]
    int2*  pairs = (int2*)(stats + S0SZ + 4 * SLSZ);

    float* S0 = stats;
    float* S1 = stats + S0SZ;
    float* S2 = S1 + SLSZ;
    float* S3 = S2 + SLSZ;
    float* S4 = S3 + SLSZ;

    // no hipMemsetAsync: S0 is exclusive-write, S1-S4 zeroed inside k_init
    k_init<<<IBLK, 512, 0, stream>>>(x, w_in, b_in, w1, w2, w_out, wbf,
                                     pairs, out, buf0, stats);

    k_gemm<<<812, 256, 0, stream>>>(buf0, S0, IBLK, g1, beta1,
                                    wbf + 0 * 65536, bias1, nullptr, buf1, S1);
    k_gemm<<<812, 256, 0, stream>>>(buf1, S1, NCPY, g2, beta2,
                                    wbf + 2 * 65536, bias2, buf0, buf2, S2);
    k_gemm<<<812, 256, 0, stream>>>(buf2, S2, NCPY, g1 + HID, beta1 + HID,
                                    wbf + 1 * 65536, bias1 + HID, nullptr, buf1, S3);
    k_gemm<<<812, 256, 0, stream>>>(buf1, S3, NCPY, g2 + HID, beta2 + HID,
                                    wbf + 3 * 65536, bias2 + HID, buf2, buf0, S4);
    k_gout<<<406, 256, 0, stream>>>(buf0, S4, fg, fbeta,
                                    wbf + 4 * 65536, b_out, pairs, out);
}

// Round 16
// 102.896 us; speedup vs baseline: 1.0138x; 1.0138x over previous
//
#include <hip/hip_runtime.h>

#define RTOT 12960      // 4 * 3240 rows
#define PAIRS 3240
#define NB_VAR 81
#define HID 256
#define EPS 1e-5f

#define BM 64
#define BN 64
#define LDB 264        // sB row stride in bf16: 528 B/row -> 2-way bank alias max (free per m136)
#define NCPY 16        // stats split copies; layout [q][col][cp] -> coeffs reads are float4
#define SLOT 8192      // floats per stats slot: 2 * 256 * 16

using bf8   = __attribute__((ext_vector_type(8))) short;
using f32x4 = __attribute__((ext_vector_type(4))) float;

__device__ inline ushort f2bf(float f) {
    union { float f; unsigned u; } c; c.f = f;
    unsigned u = c.u + 0x7fffu + ((c.u >> 16) & 1u);
    return (ushort)(u >> 16);
}
__device__ inline float bf2f(ushort h) {
    union { unsigned u; float f; } c; c.u = (unsigned)h << 16;
    return c.f;
}
__device__ inline unsigned pk2(float a, float b) {
    return (unsigned)f2bf(a) | ((unsigned)f2bf(b) << 16);
}
// upper-tri pair from linear index p (0..3239)
__device__ inline int2 pair_of(int p) {
    int i = (int)((161.0 - sqrt(25921.0 - 8.0 * (double)p)) * 0.5);
    if (i < 0) i = 0;
    while ((161 * (i + 1) - (i + 1) * (i + 1)) / 2 <= p) i++;
    while ((161 * i - i * i) / 2 > p) i--;
    int j = i + 1 + (p - (161 * i - i * i) / 2);
    return make_int2(i, j);
}

// sum the 16 split copies (layout [q][col][cp]) -> BN coefficients in LDS
__device__ __forceinline__ void coeffs(const float* __restrict__ st,
                                       const float* __restrict__ g,
                                       const float* __restrict__ beta,
                                       float* sS, float* sT) {
    int tid = threadIdx.x;
    float s = 0.f, q = 0.f;
#pragma unroll
    for (int c4 = 0; c4 < 4; c4++) {
        float4 a = *(const float4*)&st[tid * 16 + c4 * 4];
        s += (a.x + a.y) + (a.z + a.w);
    }
#pragma unroll
    for (int c4 = 0; c4 < 4; c4++) {
        float4 a = *(const float4*)&st[4096 + tid * 16 + c4 * 4];
        q += (a.x + a.y) + (a.z + a.w);
    }
    float m = s * (1.f / RTOT);
    float v = q * (1.f / RTOT) - m * m;
    float sc = g[tid] * rsqrtf(v + EPS);
    sS[tid] = sc;
    sT[tid] = fmaf(-m, sc, beta[tid]);
}

// A-fragment: 8 bf16 from global, BN+ReLU in registers, repack bf16
__device__ __forceinline__ bf8 ldA(const ushort* xr, int kst,
                                   const float* sS, const float* sT) {
    float4 s0 = *(const float4*)&sS[kst], s1 = *(const float4*)&sS[kst + 4];
    float4 t0 = *(const float4*)&sT[kst], t1 = *(const float4*)&sT[kst + 4];
    ushort xv[8];
    *(uint4*)xv = *(const uint4*)(xr + kst);
    unsigned pk[4];
    pk[0] = pk2(fmaxf(fmaf(bf2f(xv[0]), s0.x, t0.x), 0.f),
                fmaxf(fmaf(bf2f(xv[1]), s0.y, t0.y), 0.f));
    pk[1] = pk2(fmaxf(fmaf(bf2f(xv[2]), s0.z, t0.z), 0.f),
                fmaxf(fmaf(bf2f(xv[3]), s0.w, t0.w), 0.f));
    pk[2] = pk2(fmaxf(fmaf(bf2f(xv[4]), s1.x, t1.x), 0.f),
                fmaxf(fmaf(bf2f(xv[5]), s1.y, t1.y), 0.f));
    pk[3] = pk2(fmaxf(fmaf(bf2f(xv[6]), s1.z, t1.z), 0.f),
                fmaxf(fmaf(bf2f(xv[7]), s1.w, t1.w), 0.f));
    return *(bf8*)pk;
}

// ---------------- init: weights->bf16, pairs, out-diag, proj + stats0, zero slots 1-4 ----------
__global__ __launch_bounds__(256) void k_init(
        const float* __restrict__ x, const float* __restrict__ w_in,
        const float* __restrict__ b_in,
        const float* __restrict__ w1, const float* __restrict__ w2,
        const float* __restrict__ w_out, ushort* __restrict__ wbf,
        int2* __restrict__ pairs, float* __restrict__ out,
        ushort* __restrict__ h0, float* __restrict__ stats) {
    __shared__ float feat[32][4];
    int tid = threadIdx.x;
    int gtid = blockIdx.x * 256 + tid;

    for (int i = gtid; i < 262144 + 81 * 256; i += 405 * 256) {
        float v;
        if (i < 131072)      v = w1[i];
        else if (i < 262144) v = w2[i - 131072];
        else                 v = w_out[i - 262144];
        wbf[i] = f2bf(v);
    }
    if (gtid < 4 * NB_VAR * 81) {
        int b = gtid / (NB_VAR * 81);
        int rem = gtid - b * (NB_VAR * 81);
        int i = rem / 81, t = rem - i * 81;
        out[((size_t)(b * NB_VAR + i) * NB_VAR + i) * 81 + t] = 0.f;
    }
    // zero stats slots 1-4 (atomics to them happen only in later, stream-ordered kernels)
    if (gtid < 4 * SLOT)
        stats[SLOT + gtid] = 0.f;

    int r0 = blockIdx.x * 32;
    if (tid < 32) {
        int r = r0 + tid;
        int b = r / PAIRS, p = r - b * PAIRS;
        int2 ij = pair_of(p);
        if (r < PAIRS) pairs[r] = ij;
        const float* xb = x + b * NB_VAR * 2;
        feat[tid][0] = xb[ij.x * 2 + 0];
        feat[tid][1] = xb[ij.x * 2 + 1];
        feat[tid][2] = xb[ij.y * 2 + 0];
        feat[tid][3] = xb[ij.y * 2 + 1];
    }
    __syncthreads();
    float4 w = ((const float4*)w_in)[tid];
    float bi = b_in[tid];
    float s = 0.f, s2 = 0.f;
    for (int t = 0; t < 32; t++) {
        float v = fmaf(feat[t][0], w.x, fmaf(feat[t][1], w.y,
                  fmaf(feat[t][2], w.z, fmaf(feat[t][3], w.w, bi))));
        v = fmaxf(v, 0.f);
        h0[(size_t)(r0 + t) * HID + tid] = f2bf(v);
        s += v; s2 += v * v;
    }
    int cp = blockIdx.x & (NCPY - 1);
    atomicAdd(&stats[tid * 16 + cp], s);
    atomicAdd(&stats[4096 + tid * 16 + cp], s2);
}

// ---------------- MFMA GEMM (R12): LDS-B, disjoint wave strips, XCD swizzle ----------------
__global__ __launch_bounds__(256) void k_gemm(
        const ushort* __restrict__ X, const float* __restrict__ stin,
        const float* __restrict__ g, const float* __restrict__ beta,
        const ushort* __restrict__ Wb, const float* __restrict__ bias,
        const ushort* __restrict__ res, ushort* __restrict__ Y,
        float* __restrict__ stout) {
    __shared__ ushort sB[BN * LDB];
    __shared__ float sS[HID], sT[HID];
    __shared__ float sCS[4][BN], sCQ[4][BN];

    int tid = threadIdx.x;
    coeffs(stin, g, beta, sS, sT);

    int id = blockIdx.x, bx, by;
    if (id < 800) { bx = (id >> 5) * 8 + (id & 7); by = (id >> 3) & 3; }
    else          { int j = id - 800; bx = 200 + (j >> 2); by = j & 3; }

    int bm0 = bx * BM;
    int bn0 = by * BN;
    {   // stage whole B tile: 64 rows x 256 k
        int row = tid >> 2, cq = tid & 3;
#pragma unroll
        for (int s = 0; s < 8; s++) {
            int col = cq * 8 + s * 32;
            uint4 wv = *(const uint4*)(Wb + (size_t)(bn0 + row) * HID + col);
            *(uint4*)&sB[row * LDB + col] = wv;
        }
    }
    __syncthreads();

    int lane = tid & 63, w = tid >> 6;
    int r16 = lane & 15, kq = lane >> 4;

    f32x4 acc[4] = {};
    int ar = min(bm0 + w * 16 + r16, RTOT - 1);
    const ushort* xr = X + (size_t)ar * HID;

#pragma unroll
    for (int kk = 0; kk < 8; kk++) {
        int kst = kk * 32 + kq * 8;
        bf8 af = ldA(xr, kst, sS, sT);
        bf8 b0 = *(const bf8*)&sB[(0 * 16 + r16) * LDB + kst];
        bf8 b1 = *(const bf8*)&sB[(1 * 16 + r16) * LDB + kst];
        bf8 b2 = *(const bf8*)&sB[(2 * 16 + r16) * LDB + kst];
        bf8 b3 = *(const bf8*)&sB[(3 * 16 + r16) * LDB + kst];
        acc[0] = __builtin_amdgcn_mfma_f32_16x16x32_bf16(af, b0, acc[0], 0, 0, 0);
        acc[1] = __builtin_amdgcn_mfma_f32_16x16x32_bf16(af, b1, acc[1], 0, 0, 0);
        acc[2] = __builtin_amdgcn_mfma_f32_16x16x32_bf16(af, b2, acc[2], 0, 0, 0);
        acc[3] = __builtin_amdgcn_mfma_f32_16x16x32_bf16(af, b3, acc[3], 0, 0, 0);
    }

    // epilogue: bias (+res), store bf16, column stats
    int rb = bm0 + w * 16;
#pragma unroll
    for (int n = 0; n < 4; n++) {
        int col = bn0 + n * 16 + r16;
        float bv = bias[col];
        float cs = 0.f, cq2 = 0.f;
#pragma unroll
        for (int i = 0; i < 4; i++) {
            int r = rb + kq * 4 + i;
            if (r < RTOT) {
                float v = acc[n][i] + bv;
                if (res) v += bf2f(res[(size_t)r * HID + col]);
                Y[(size_t)r * HID + col] = f2bf(v);
                cs += v; cq2 += v * v;
            }
        }
        cs += __shfl_xor(cs, 16); cq2 += __shfl_xor(cq2, 16);
        cs += __shfl_xor(cs, 32); cq2 += __shfl_xor(cq2, 32);
        if (lane < 16) {
            sCS[w][n * 16 + lane] = cs; sCQ[w][n * 16 + lane] = cq2;
        }
    }
    __syncthreads();
    if (tid < 2 * BN) {
        int col = tid & (BN - 1), q = tid >> 6;
        float v = q ? (sCQ[0][col] + sCQ[1][col] + sCQ[2][col] + sCQ[3][col])
                    : (sCS[0][col] + sCS[1][col] + sCS[2][col] + sCS[3][col]);
        int cp = id & (NCPY - 1);
        atomicAdd(&stout[q * 4096 + (bn0 + col) * 16 + cp], v);
    }
}

// ---------------- final GEMM (N=81), wave strips, fused symmetric scatter ----------------
__global__ __launch_bounds__(256) void k_gout(
        const ushort* __restrict__ X, const float* __restrict__ stin,
        const float* __restrict__ g, const float* __restrict__ beta,
        const ushort* __restrict__ Wb, const float* __restrict__ b_out,
        const int2* __restrict__ pairs, float* __restrict__ out) {
    __shared__ ushort sB[BN * LDB];
    __shared__ float sS[HID], sT[HID];

    int tid = threadIdx.x;
    coeffs(stin, g, beta, sS, sT);

    int id = blockIdx.x, bx, by;
    if (id < 400) { bx = (id >> 4) * 8 + (id & 7); by = (id >> 3) & 1; }
    else          { int j = id - 400; bx = 200 + (j >> 1); by = j & 1; }

    int bm0 = bx * BM;
    int bn0 = by * BN;
    {
        int row = tid >> 2, cq = tid & 3;
        int gn = bn0 + row; gn = gn < 81 ? gn : 80;
#pragma unroll
        for (int s = 0; s < 8; s++) {
            int col = cq * 8 + s * 32;
            uint4 wv = *(const uint4*)(Wb + (size_t)gn * HID + col);
            *(uint4*)&sB[row * LDB + col] = wv;
        }
    }
    __syncthreads();

    int lane = tid & 63, w = tid >> 6;
    int r16 = lane & 15, kq = lane >> 4;

    f32x4 acc[4] = {};
    int ar = min(bm0 + w * 16 + r16, RTOT - 1);
    const ushort* xr = X + (size_t)ar * HID;

#pragma unroll
    for (int kk = 0; kk < 8; kk++) {
        int kst = kk * 32 + kq * 8;
        bf8 af = ldA(xr, kst, sS, sT);
        bf8 b0 = *(const bf8*)&sB[(0 * 16 + r16) * LDB + kst];
        bf8 b1 = *(const bf8*)&sB[(1 * 16 + r16) * LDB + kst];
        bf8 b2 = *(const bf8*)&sB[(2 * 16 + r16) * LDB + kst];
        bf8 b3 = *(const bf8*)&sB[(3 * 16 + r16) * LDB + kst];
        acc[0] = __builtin_amdgcn_mfma_f32_16x16x32_bf16(af, b0, acc[0], 0, 0, 0);
        acc[1] = __builtin_amdgcn_mfma_f32_16x16x32_bf16(af, b1, acc[1], 0, 0, 0);
        acc[2] = __builtin_amdgcn_mfma_f32_16x16x32_bf16(af, b2, acc[2], 0, 0, 0);
        acc[3] = __builtin_amdgcn_mfma_f32_16x16x32_bf16(af, b3, acc[3], 0, 0, 0);
    }

    int rb = bm0 + w * 16;
#pragma unroll
    for (int n = 0; n < 4; n++) {
        int t = bn0 + n * 16 + r16;
        if (t >= 81) continue;
        int gi = t / 9, gj = t - gi * 9;
        int ttr = gj * 9 + gi;
        float bb = b_out[t];
#pragma unroll
        for (int i = 0; i < 4; i++) {
            int r = rb + kq * 4 + i;
            if (r >= RTOT) continue;
            int b = r / PAIRS, p = r - b * PAIRS;
            int2 ij = pairs[p];
            size_t base1 = ((size_t)(b * NB_VAR + ij.x) * NB_VAR + ij.y) * 81;
            size_t base2 = ((size_t)(b * NB_VAR + ij.y) * NB_VAR + ij.x) * 81;
            float v = acc[n][i] + bb;
            out[base1 + t] = v;
            out[base2 + ttr] = v;
        }
    }
}

extern "C" void kernel_launch(void* const* d_in, const int* in_sizes, int n_in,
                              void* d_out, int out_size, void* d_ws, size_t ws_size,
                              hipStream_t stream) {
    const float* x     = (const float*)d_in[0];
    const float* w_in  = (const float*)d_in[1];
    const float* b_in  = (const float*)d_in[2];
    const float* g1    = (const float*)d_in[3];
    const float* beta1 = (const float*)d_in[4];
    const float* w1    = (const float*)d_in[5];
    const float* bias1 = (const float*)d_in[6];
    const float* g2    = (const float*)d_in[7];
    const float* beta2 = (const float*)d_in[8];
    const float* w2    = (const float*)d_in[9];
    const float* bias2 = (const float*)d_in[10];
    const float* fg    = (const float*)d_in[11];
    const float* fbeta = (const float*)d_in[12];
    const float* w_out = (const float*)d_in[13];
    const float* b_out = (const float*)d_in[14];
    float* out = (float*)d_out;

    ushort* buf0 = (ushort*)d_ws;
    ushort* buf1 = buf0 + (size_t)RTOT * HID;
    ushort* buf2 = buf1 + (size_t)RTOT * HID;
    ushort* wbf  = buf2 + (size_t)RTOT * HID;   // 5*65536 elems (w1 | w2 | w_out row-major bf16)
    float* stats = (float*)(wbf + 5 * 65536);   // 5 slots x 8192 floats, layout [q][col][cp]
    int2*  pairs = (int2*)(stats + 5 * SLOT);
    // wbf layout: w1_0 @0, w1_1 @65536, w2_0 @131072, w2_1 @196608, w_out @262144

    float* S0 = stats;
    float* S1 = stats + 1 * SLOT;
    float* S2 = stats + 2 * SLOT;
    float* S3 = stats + 3 * SLOT;
    float* S4 = stats + 4 * SLOT;

    hipMemsetAsync(S0, 0, SLOT * sizeof(float), stream);   // S1-S4 zeroed inside k_init
    k_init<<<405, 256, 0, stream>>>(x, w_in, b_in, w1, w2, w_out, wbf,
                                    pairs, out, buf0, stats);

    k_gemm<<<812, 256, 0, stream>>>(buf0, S0, g1, beta1,
                                    wbf + 0 * 65536, bias1, nullptr, buf1, S1);
    k_gemm<<<812, 256, 0, stream>>>(buf1, S1, g2, beta2,
                                    wbf + 2 * 65536, bias2, buf0, buf2, S2);
    k_gemm<<<812, 256, 0, stream>>>(buf2, S2, g1 + HID, beta1 + HID,
                                    wbf + 1 * 65536, bias1 + HID, nullptr, buf1, S3);
    k_gemm<<<812, 256, 0, stream>>>(buf1, S3, g2 + HID, beta2 + HID,
                                    wbf + 3 * 65536, bias2 + HID, buf2, buf0, S4);
    k_gout<<<406, 256, 0, stream>>>(buf0, S4, fg, fbeta,
                                    wbf + 4 * 65536, b_out, pairs, out);
}

// Round 17
// 83.141 us; speedup vs baseline: 1.2547x; 1.2376x over previous
//
#include <hip/hip_runtime.h>

#define RTOT 12960      // 4 * 3240 rows
#define PAIRS 3240
#define NB_VAR 81
#define HID 256
#define EPS 1e-5f

#define BM 64
#define BN 64
#define LDB 264        // sB row stride in bf16: 528 B/row -> 2-way bank alias max (free per m136)
#define NCPY 16        // stats split: copies 2KB apart -> DISTINCT L2 lines (R16 lesson: line-sharing re-serializes atomics)

using bf8   = __attribute__((ext_vector_type(8))) short;
using f32x4 = __attribute__((ext_vector_type(4))) float;

__device__ inline ushort f2bf(float f) {
    union { float f; unsigned u; } c; c.f = f;
    unsigned u = c.u + 0x7fffu + ((c.u >> 16) & 1u);
    return (ushort)(u >> 16);
}
__device__ inline float bf2f(ushort h) {
    union { unsigned u; float f; } c; c.u = (unsigned)h << 16;
    return c.f;
}
__device__ inline unsigned pk2(float a, float b) {
    return (unsigned)f2bf(a) | ((unsigned)f2bf(b) << 16);
}
// upper-tri pair from linear index p (0..3239)
__device__ inline int2 pair_of(int p) {
    int i = (int)((161.0 - sqrt(25921.0 - 8.0 * (double)p)) * 0.5);
    if (i < 0) i = 0;
    while ((161 * (i + 1) - (i + 1) * (i + 1)) / 2 <= p) i++;
    while ((161 * i - i * i) / 2 > p) i--;
    int j = i + 1 + (p - (161 * i - i * i) / 2);
    return make_int2(i, j);
}

// sum the NCPY split copies -> BN coefficients in LDS
__device__ __forceinline__ void coeffs(const float* __restrict__ st,
                                       const float* __restrict__ g,
                                       const float* __restrict__ beta,
                                       float* sS, float* sT) {
    int tid = threadIdx.x;
    float s = 0.f, q = 0.f;
#pragma unroll
    for (int cp = 0; cp < NCPY; cp++) {
        s += st[cp * 512 + tid];
        q += st[cp * 512 + 256 + tid];
    }
    float m = s * (1.f / RTOT);
    float v = q * (1.f / RTOT) - m * m;
    float sc = g[tid] * rsqrtf(v + EPS);
    sS[tid] = sc;
    sT[tid] = fmaf(-m, sc, beta[tid]);
}

// A-fragment: 8 bf16 loaded from global, BN+ReLU in registers, repack bf16
__device__ __forceinline__ bf8 ldA(const ushort* xr, int kst,
                                   const float* sS, const float* sT) {
    float4 s0 = *(const float4*)&sS[kst], s1 = *(const float4*)&sS[kst + 4];
    float4 t0 = *(const float4*)&sT[kst], t1 = *(const float4*)&sT[kst + 4];
    ushort xv[8];
    *(uint4*)xv = *(const uint4*)(xr + kst);
    unsigned pk[4];
    pk[0] = pk2(fmaxf(fmaf(bf2f(xv[0]), s0.x, t0.x), 0.f),
                fmaxf(fmaf(bf2f(xv[1]), s0.y, t0.y), 0.f));
    pk[1] = pk2(fmaxf(fmaf(bf2f(xv[2]), s0.z, t0.z), 0.f),
                fmaxf(fmaf(bf2f(xv[3]), s0.w, t0.w), 0.f));
    pk[2] = pk2(fmaxf(fmaf(bf2f(xv[4]), s1.x, t1.x), 0.f),
                fmaxf(fmaf(bf2f(xv[5]), s1.y, t1.y), 0.f));
    pk[3] = pk2(fmaxf(fmaf(bf2f(xv[6]), s1.z, t1.z), 0.f),
                fmaxf(fmaf(bf2f(xv[7]), s1.w, t1.w), 0.f));
    return *(bf8*)pk;
}

// ---------------- init: weights->bf16, pairs, zero out-diag, input proj + stats0 ----------------
__global__ __launch_bounds__(256) void k_init(
        const float* __restrict__ x, const float* __restrict__ w_in,
        const float* __restrict__ b_in,
        const float* __restrict__ w1, const float* __restrict__ w2,
        const float* __restrict__ w_out, ushort* __restrict__ wbf,
        int2* __restrict__ pairs, float* __restrict__ out,
        ushort* __restrict__ h0, float* __restrict__ st) {
    __shared__ float feat[32][4];
    int tid = threadIdx.x;
    int gtid = blockIdx.x * 256 + tid;

    for (int i = gtid; i < 262144 + 81 * 256; i += 405 * 256) {
        float v;
        if (i < 131072)      v = w1[i];
        else if (i < 262144) v = w2[i - 131072];
        else                 v = w_out[i - 262144];
        wbf[i] = f2bf(v);
    }
    if (gtid < 4 * NB_VAR * 81) {
        int b = gtid / (NB_VAR * 81);
        int rem = gtid - b * (NB_VAR * 81);
        int i = rem / 81, t = rem - i * 81;
        out[((size_t)(b * NB_VAR + i) * NB_VAR + i) * 81 + t] = 0.f;
    }

    int r0 = blockIdx.x * 32;
    if (tid < 32) {
        int r = r0 + tid;
        int b = r / PAIRS, p = r - b * PAIRS;
        int2 ij = pair_of(p);
        if (r < PAIRS) pairs[r] = ij;
        const float* xb = x + b * NB_VAR * 2;
        feat[tid][0] = xb[ij.x * 2 + 0];
        feat[tid][1] = xb[ij.x * 2 + 1];
        feat[tid][2] = xb[ij.y * 2 + 0];
        feat[tid][3] = xb[ij.y * 2 + 1];
    }
    __syncthreads();
    float4 w = ((const float4*)w_in)[tid];
    float bi = b_in[tid];
    float s = 0.f, s2 = 0.f;
    for (int t = 0; t < 32; t++) {
        float v = fmaf(feat[t][0], w.x, fmaf(feat[t][1], w.y,
                  fmaf(feat[t][2], w.z, fmaf(feat[t][3], w.w, bi))));
        v = fmaxf(v, 0.f);
        h0[(size_t)(r0 + t) * HID + tid] = f2bf(v);
        s += v; s2 += v * v;
    }
    int cp = blockIdx.x & (NCPY - 1);
    atomicAdd(&st[cp * 512 + tid], s);
    atomicAdd(&st[cp * 512 + 256 + tid], s2);
}

// ---------------- MFMA GEMM: disjoint 16-row wave strips, LDS-B, XCD swizzle ----------------
__global__ __launch_bounds__(256) void k_gemm(
        const ushort* __restrict__ X, const float* __restrict__ stin,
        const float* __restrict__ g, const float* __restrict__ beta,
        const ushort* __restrict__ Wb, const float* __restrict__ bias,
        const ushort* __restrict__ res, ushort* __restrict__ Y,
        float* __restrict__ stout) {
    __shared__ ushort sB[BN * LDB];
    __shared__ float sS[HID], sT[HID];
    __shared__ float sCS[4][BN], sCQ[4][BN];

    int tid = threadIdx.x;
    coeffs(stin, g, beta, sS, sT);

    int id = blockIdx.x, bx, by;
    if (id < 800) { bx = (id >> 5) * 8 + (id & 7); by = (id >> 3) & 3; }
    else          { int j = id - 800; bx = 200 + (j >> 2); by = j & 3; }

    int bm0 = bx * BM;
    int bn0 = by * BN;
    {   // stage whole B tile: 64 rows x 256 k
        int row = tid >> 2, cq = tid & 3;
#pragma unroll
        for (int s = 0; s < 8; s++) {
            int col = cq * 8 + s * 32;
            uint4 wv = *(const uint4*)(Wb + (size_t)(bn0 + row) * HID + col);
            *(uint4*)&sB[row * LDB + col] = wv;
        }
    }
    __syncthreads();

    int lane = tid & 63, w = tid >> 6;
    int r16 = lane & 15, kq = lane >> 4;

    f32x4 acc[4] = {};
    int ar = min(bm0 + w * 16 + r16, RTOT - 1);
    const ushort* xr = X + (size_t)ar * HID;

#pragma unroll
    for (int kk = 0; kk < 8; kk++) {
        int kst = kk * 32 + kq * 8;
        bf8 af = ldA(xr, kst, sS, sT);
        bf8 b0 = *(const bf8*)&sB[(0 * 16 + r16) * LDB + kst];
        bf8 b1 = *(const bf8*)&sB[(1 * 16 + r16) * LDB + kst];
        bf8 b2 = *(const bf8*)&sB[(2 * 16 + r16) * LDB + kst];
        bf8 b3 = *(const bf8*)&sB[(3 * 16 + r16) * LDB + kst];
        acc[0] = __builtin_amdgcn_mfma_f32_16x16x32_bf16(af, b0, acc[0], 0, 0, 0);
        acc[1] = __builtin_amdgcn_mfma_f32_16x16x32_bf16(af, b1, acc[1], 0, 0, 0);
        acc[2] = __builtin_amdgcn_mfma_f32_16x16x32_bf16(af, b2, acc[2], 0, 0, 0);
        acc[3] = __builtin_amdgcn_mfma_f32_16x16x32_bf16(af, b3, acc[3], 0, 0, 0);
    }

    // epilogue: bias (+res), store bf16, column stats
    int rb = bm0 + w * 16;
#pragma unroll
    for (int n = 0; n < 4; n++) {
        int col = bn0 + n * 16 + r16;
        float bv = bias[col];
        float cs = 0.f, cq2 = 0.f;
#pragma unroll
        for (int i = 0; i < 4; i++) {
            int r = rb + kq * 4 + i;
            if (r < RTOT) {
                float v = acc[n][i] + bv;
                if (res) v += bf2f(res[(size_t)r * HID + col]);
                Y[(size_t)r * HID + col] = f2bf(v);
                cs += v; cq2 += v * v;
            }
        }
        cs += __shfl_xor(cs, 16); cq2 += __shfl_xor(cq2, 16);
        cs += __shfl_xor(cs, 32); cq2 += __shfl_xor(cq2, 32);
        if (lane < 16) {
            sCS[w][n * 16 + lane] = cs; sCQ[w][n * 16 + lane] = cq2;
        }
    }
    __syncthreads();
    if (tid < 2 * BN) {
        int col = tid & (BN - 1), q = tid >> 6;
        float v = q ? (sCQ[0][col] + sCQ[1][col] + sCQ[2][col] + sCQ[3][col])
                    : (sCS[0][col] + sCS[1][col] + sCS[2][col] + sCS[3][col]);
        int cp = id & (NCPY - 1);
        atomicAdd(&stout[cp * 512 + q * 256 + bn0 + col], v);
    }
}

// ---------------- final GEMM (N=81), disjoint wave strips, fused scatter ----------------
__global__ __launch_bounds__(256) void k_gout(
        const ushort* __restrict__ X, const float* __restrict__ stin,
        const float* __restrict__ g, const float* __restrict__ beta,
        const ushort* __restrict__ Wb, const float* __restrict__ b_out,
        const int2* __restrict__ pairs, float* __restrict__ out) {
    __shared__ ushort sB[BN * LDB];
    __shared__ float sS[HID], sT[HID];

    int tid = threadIdx.x;
    coeffs(stin, g, beta, sS, sT);

    int id = blockIdx.x, bx, by;
    if (id < 400) { bx = (id >> 4) * 8 + (id & 7); by = (id >> 3) & 1; }
    else          { int j = id - 400; bx = 200 + (j >> 1); by = j & 1; }

    int bm0 = bx * BM;
    int bn0 = by * BN;
    {
        int row = tid >> 2, cq = tid & 3;
        int gn = bn0 + row; gn = gn < 81 ? gn : 80;
#pragma unroll
        for (int s = 0; s < 8; s++) {
            int col = cq * 8 + s * 32;
            uint4 wv = *(const uint4*)(Wb + (size_t)gn * HID + col);
            *(uint4*)&sB[row * LDB + col] = wv;
        }
    }
    __syncthreads();

    int lane = tid & 63, w = tid >> 6;
    int r16 = lane & 15, kq = lane >> 4;

    f32x4 acc[4] = {};
    int ar = min(bm0 + w * 16 + r16, RTOT - 1);
    const ushort* xr = X + (size_t)ar * HID;

#pragma unroll
    for (int kk = 0; kk < 8; kk++) {
        int kst = kk * 32 + kq * 8;
        bf8 af = ldA(xr, kst, sS, sT);
        bf8 b0 = *(const bf8*)&sB[(0 * 16 + r16) * LDB + kst];
        bf8 b1 = *(const bf8*)&sB[(1 * 16 + r16) * LDB + kst];
        bf8 b2 = *(const bf8*)&sB[(2 * 16 + r16) * LDB + kst];
        bf8 b3 = *(const bf8*)&sB[(3 * 16 + r16) * LDB + kst];
        acc[0] = __builtin_amdgcn_mfma_f32_16x16x32_bf16(af, b0, acc[0], 0, 0, 0);
        acc[1] = __builtin_amdgcn_mfma_f32_16x16x32_bf16(af, b1, acc[1], 0, 0, 0);
        acc[2] = __builtin_amdgcn_mfma_f32_16x16x32_bf16(af, b2, acc[2], 0, 0, 0);
        acc[3] = __builtin_amdgcn_mfma_f32_16x16x32_bf16(af, b3, acc[3], 0, 0, 0);
    }

    int rb = bm0 + w * 16;
#pragma unroll
    for (int n = 0; n < 4; n++) {
        int t = bn0 + n * 16 + r16;
        if (t >= 81) continue;
        int gi = t / 9, gj = t - gi * 9;
        int ttr = gj * 9 + gi;
        float bb = b_out[t];
#pragma unroll
        for (int i = 0; i < 4; i++) {
            int r = rb + kq * 4 + i;
            if (r >= RTOT) continue;
            int b = r / PAIRS, p = r - b * PAIRS;
            int2 ij = pairs[p];
            size_t base1 = ((size_t)(b * NB_VAR + ij.x) * NB_VAR + ij.y) * 81;
            size_t base2 = ((size_t)(b * NB_VAR + ij.y) * NB_VAR + ij.x) * 81;
            float v = acc[n][i] + bb;
            out[base1 + t] = v;
            out[base2 + ttr] = v;
        }
    }
}

extern "C" void kernel_launch(void* const* d_in, const int* in_sizes, int n_in,
                              void* d_out, int out_size, void* d_ws, size_t ws_size,
                              hipStream_t stream) {
    const float* x     = (const float*)d_in[0];
    const float* w_in  = (const float*)d_in[1];
    const float* b_in  = (const float*)d_in[2];
    const float* g1    = (const float*)d_in[3];
    const float* beta1 = (const float*)d_in[4];
    const float* w1    = (const float*)d_in[5];
    const float* bias1 = (const float*)d_in[6];
    const float* g2    = (const float*)d_in[7];
    const float* beta2 = (const float*)d_in[8];
    const float* w2    = (const float*)d_in[9];
    const float* bias2 = (const float*)d_in[10];
    const float* fg    = (const float*)d_in[11];
    const float* fbeta = (const float*)d_in[12];
    const float* w_out = (const float*)d_in[13];
    const float* b_out = (const float*)d_in[14];
    float* out = (float*)d_out;

    ushort* buf0 = (ushort*)d_ws;
    ushort* buf1 = buf0 + (size_t)RTOT * HID;
    ushort* buf2 = buf1 + (size_t)RTOT * HID;
    ushort* wbf  = buf2 + (size_t)RTOT * HID;   // 5*65536 elems
    float* stats = (float*)(wbf + 5 * 65536);   // 5 slots x NCPY x 512
    int2*  pairs = (int2*)(stats + 5 * NCPY * 512);
    // wbf layout: w1_0 @0, w1_1 @65536, w2_0 @131072, w2_1 @196608, w_out @262144

    hipMemsetAsync(stats, 0, 5 * NCPY * 512 * sizeof(float), stream);
    k_init<<<405, 256, 0, stream>>>(x, w_in, b_in, w1, w2, w_out, wbf,
                                    pairs, out, buf0, stats + 0 * NCPY * 512);

    k_gemm<<<812, 256, 0, stream>>>(buf0, stats + 0 * NCPY * 512, g1, beta1,
                                    wbf + 0 * 65536, bias1, nullptr, buf1, stats + 1 * NCPY * 512);
    k_gemm<<<812, 256, 0, stream>>>(buf1, stats + 1 * NCPY * 512, g2, beta2,
                                    wbf + 2 * 65536, bias2, buf0, buf2, stats + 2 * NCPY * 512);
    k_gemm<<<812, 256, 0, stream>>>(buf2, stats + 2 * NCPY * 512, g1 + HID, beta1 + HID,
                                    wbf + 1 * 65536, bias1 + HID, nullptr, buf1, stats + 3 * NCPY * 512);
    k_gemm<<<812, 256, 0, stream>>>(buf1, stats + 3 * NCPY * 512, g2 + HID, beta2 + HID,
                                    wbf + 3 * 65536, bias2 + HID, buf2, buf0, stats + 4 * NCPY * 512);
    k_gout<<<406, 256, 0, stream>>>(buf0, stats + 4 * NCPY * 512, fg, fbeta,
                                    wbf + 4 * 65536, b_out, pairs, out);
}